// Round 11
// baseline (1696.739 us; speedup 1.0000x reference)
//
#include <hip/hip_runtime.h>

#define D 256
#define BM 64
#define BN 64
#define BK 16

typedef unsigned short u16;
typedef unsigned int u32;
typedef __attribute__((ext_vector_type(8))) short short8;
typedef __attribute__((ext_vector_type(4))) float f32x4;
typedef __attribute__((ext_vector_type(16))) float f32x16;

// ---------------- bf16 <-> f32, split-pack ----------------
__device__ __forceinline__ float b2f(u16 u) {
    return __uint_as_float(((u32)u) << 16);
}
__device__ __forceinline__ u16 f2b(float f) {
    u32 u = __float_as_uint(f);
    return (u16)((u + 0x7FFFu + ((u >> 16) & 1u)) >> 16);  // RNE
}
__device__ __forceinline__ u32 packf(float v) {
    u16 h = f2b(v);
    u16 l = f2b(v - b2f(h));
    return ((u32)h << 16) | l;
}
__device__ __forceinline__ float unpackf(u32 p) {
    return b2f((u16)(p >> 16)) + b2f((u16)(p & 0xffffu));
}
template<typename T> __device__ __forceinline__ float ld1(const T* p);
template<> __device__ __forceinline__ float ld1<float>(const float* p) { return *p; }
template<> __device__ __forceinline__ float ld1<u16>(const u16* p) { return b2f(*p); }

// ---------------- ordered-uint float atomic max ----------------
__device__ __forceinline__ u32 f2ord(float f) {
    u32 b = __float_as_uint(f);
    return (b & 0x80000000u) ? ~b : (b | 0x80000000u);
}
__device__ __forceinline__ float ord2f(u32 u) {
    return (u & 0x80000000u) ? __uint_as_float(u & 0x7fffffffu)
                             : __uint_as_float(~u);
}

__device__ __forceinline__ float wred(float v) {
#pragma unroll
    for (int m = 32; m; m >>= 1) v += __shfl_xor(v, m);
    return v;
}

// async global(16B/lane) -> LDS (wave-uniform base + lane*16)
__device__ __forceinline__ void gl_lds16(const u16* g, u16* l) {
    __builtin_amdgcn_global_load_lds(
        (__attribute__((address_space(1))) void*)(u16*)g,
        (__attribute__((address_space(3))) void*)l, 16, 0, 0);
}

// ======== gemm2: single-term (hi-only W) MFMA GEMM (head MLP) ========
// C = act(A[M,K] @ W[N,K]^T + b). A bf16 u16; W hi-plane u16.
// 512 threads: block tile 128x256, wave grid 2x4, wave tile 64x64.
// 32x32x16 MFMA. M%128==0, N%256==0, K%32==0.
// Epilogue: per-wave LDS transpose (sWh reuse AFTER __syncthreads — fixes the
// R6 race where other waves still read sWh) -> 16B/lane full-line stores.
template<int ACT>
__global__ __launch_bounds__(512, 4)
void gemm2(const u16* __restrict__ A, const u16* __restrict__ Whi,
           const float* __restrict__ bias, u16* __restrict__ C,
           int M, int N, int K)
{
    __shared__ u16 sA[128 * 32];       // 8 KB
    __shared__ u16 sWh[256 * 32];      // 16 KB

    const int tid  = threadIdx.x;
    const int lane = tid & 63;
    const int w    = tid >> 6;             // wave 0..7
    const int wm   = (w & 1) * 64;         // wave row-origin (0/64)
    const int wn   = (w >> 1) * 64;        // wave col-origin (0/64/128/192)
    const int row0 = blockIdx.x * 128;
    const int col0 = blockIdx.y * 256;

    f32x16 acc[2][2];
#pragma unroll
    for (int i = 0; i < 2; ++i)
#pragma unroll
        for (int j = 0; j < 2; ++j)
#pragma unroll
            for (int r = 0; r < 16; ++r) acc[i][j][r] = 0.f;

    const int r31   = lane & 31;
    const int khalf = lane >> 5;
    const int skey  = (r31 >> 1) & 3;
    // DMA loader: lane -> (row=l>>2, LDS slot=l&3); fetched global chunk:
    const int lrow = lane >> 2;
    const int gck  = (lane & 3) ^ ((lane >> 3) & 3);

    for (int k0 = 0; k0 < K; k0 += 32) {
        // stage W hi-plane: 256 rows x 32k; 8 waves x 2 segs x 16 rows
#pragma unroll
        for (int s = 0; s < 2; ++s) {
            const int rbase = w * 32 + s * 16;          // wave-uniform
            const size_t gW = (size_t)(col0 + rbase + lrow) * K + k0 + gck * 8;
            gl_lds16(Whi + gW, sWh + rbase * 32);
        }
        // stage A via VGPR: 128x32 u16 = 8KB, 1 uint4 per thread
        {
            const int ar = tid >> 2;
            const int c = tid & 3;
            uint4 pk = *(const uint4*)(A + (size_t)(row0 + ar) * K + k0 + c * 8);
            const int slot = c ^ ((ar >> 1) & 3);
            *(uint4*)(sA + ar * 32 + slot * 8) = pk;
        }
        __syncthreads();

        short8 af[2][2], wfh[2][2];
#pragma unroll
        for (int i = 0; i < 2; ++i)
#pragma unroll
            for (int q = 0; q < 2; ++q) {
                const int slot = (q * 2 + khalf) ^ skey;
                af[i][q] = *(const short8*)(sA + (wm + i * 32 + r31) * 32 + slot * 8);
                wfh[i][q] = *(const short8*)(sWh + (wn + i * 32 + r31) * 32 + slot * 8);
            }
#pragma unroll
        for (int i = 0; i < 2; ++i)
#pragma unroll
            for (int j = 0; j < 2; ++j)
#pragma unroll
                for (int q = 0; q < 2; ++q)
                    acc[i][j] = __builtin_amdgcn_mfma_f32_32x32x16_bf16(af[i][q], wfh[j][q], acc[i][j], 0, 0, 0);
        __syncthreads();
    }

    // ---- epilogue: transpose via per-wave 2KB slice of sWh, 16B stores ----
    __syncthreads();                       // all fragment reads of sWh done
    u16* tp = sWh + w * 1024;              // 32x32 u16, per-wave disjoint
#pragma unroll
    for (int i = 0; i < 2; ++i) {
#pragma unroll
        for (int j = 0; j < 2; ++j) {
            const float bb = bias[col0 + wn + j * 32 + r31];
            // phase 1: acc -> tp (C/D: col=r31, row=4*khalf+(reg&3)+8*(reg>>2))
#pragma unroll
            for (int reg = 0; reg < 16; ++reg) {
                const int row_l = 4 * khalf + (reg & 3) + 8 * (reg >> 2);
                float v = acc[i][j][reg] + bb;
                if (ACT) v = v > 0.f ? v : 0.2f * v;
                tp[row_l * 32 + r31] = f2b(v);
            }
            __syncthreads();
            // phase 2: tp -> C, 4 lanes x 16B per row, 16 rows per iter
#pragma unroll
            for (int rr = 0; rr < 2; ++rr) {
                const int row_l = rr * 16 + (lane >> 2);
                const int c16 = (lane & 3) * 8;
                uint4 v = *(const uint4*)(tp + row_l * 32 + c16);
                *(uint4*)(C + (size_t)(row0 + wm + i * 32 + row_l) * N +
                          col0 + wn + j * 32 + c16) = v;
            }
            __syncthreads();
        }
    }
}

// ======== gemm3: 3-term split MFMA GEMM (attention path, exact split) ========
// A packed u32 (hi<<16|lo). W hi/lo planes. 16x16x32, block 128x64.
// Output: Cp packed u32, or Chi hi-only u16 (if Cp null).
__global__ __launch_bounds__(256)
void gemm3(const u32* __restrict__ Ap,
           const u16* __restrict__ Whi, const u16* __restrict__ Wlo,
           const float* __restrict__ bias,
           u32* __restrict__ Cp, u16* __restrict__ Chi,
           int M, int N, int K, int act)
{
    constexpr int TNP = 64;
    constexpr int JN = 2;
    __shared__ u16 sAhi[128 * 32];
    __shared__ u16 sAlo[128 * 32];
    __shared__ u16 sWhi[TNP * 32];
    __shared__ u16 sWlo[TNP * 32];

    const int tid  = threadIdx.x;
    const int lane = tid & 63;
    const int w    = tid >> 6;
    const int wm   = (w & 1) * 64;
    const int wn   = (w >> 1) * (TNP / 2);
    const int row0 = blockIdx.x * 128;
    const int col0 = blockIdx.y * TNP;

    f32x4 acc[4][JN];
#pragma unroll
    for (int i = 0; i < 4; ++i)
#pragma unroll
        for (int j = 0; j < JN; ++j) acc[i][j] = (f32x4){0.f, 0.f, 0.f, 0.f};

    const int lrow = lane >> 2;
    const int gck  = (lane & 3) ^ ((lane >> 3) & 3);
    const int r15 = lane & 15;
    const int rck = ((lane >> 4) ^ ((r15 >> 1) & 3)) * 8;

    for (int k0 = 0; k0 < K; k0 += 32) {
#pragma unroll
        for (int s = 0; s < TNP / 64; ++s) {
            const int rbase = s * 64 + w * 16;
            const int rt = rbase + lrow;
            const size_t gW = (size_t)(col0 + rt) * K + k0 + gck * 8;
            gl_lds16(Whi + gW, sWhi + rbase * 32);
            gl_lds16(Wlo + gW, sWlo + rbase * 32);
        }
#pragma unroll
        for (int it = 0; it < 4; ++it) {
            const int u = tid + it * 256;
            const int ar = u >> 3;
            const int pos = u & 7;
            uint4 pk = *(const uint4*)(Ap + (size_t)(row0 + ar) * K + k0 + pos * 4);
            const int slot = (pos >> 1) ^ ((ar >> 1) & 3);
            const int base = ar * 32 + slot * 8 + (pos & 1) * 4;
            ushort4 h4, l4;
            h4.x = (u16)(pk.x >> 16); l4.x = (u16)(pk.x & 0xffffu);
            h4.y = (u16)(pk.y >> 16); l4.y = (u16)(pk.y & 0xffffu);
            h4.z = (u16)(pk.z >> 16); l4.z = (u16)(pk.z & 0xffffu);
            h4.w = (u16)(pk.w >> 16); l4.w = (u16)(pk.w & 0xffffu);
            *(ushort4*)(sAhi + base) = h4;
            *(ushort4*)(sAlo + base) = l4;
        }
        __syncthreads();

        short8 ah[4], al[4], wh[JN], wl[JN];
#pragma unroll
        for (int i = 0; i < 4; ++i) {
            const int offA = (wm + i * 16 + r15) * 32 + rck;
            ah[i] = *(const short8*)(sAhi + offA);
            al[i] = *(const short8*)(sAlo + offA);
        }
#pragma unroll
        for (int j = 0; j < JN; ++j) {
            const int offW = (wn + j * 16 + r15) * 32 + rck;
            wh[j] = *(const short8*)(sWhi + offW);
            wl[j] = *(const short8*)(sWlo + offW);
        }
#pragma unroll
        for (int i = 0; i < 4; ++i)
#pragma unroll
            for (int j = 0; j < JN; ++j) {
                acc[i][j] = __builtin_amdgcn_mfma_f32_16x16x32_bf16(ah[i], wh[j], acc[i][j], 0, 0, 0);
                acc[i][j] = __builtin_amdgcn_mfma_f32_16x16x32_bf16(ah[i], wl[j], acc[i][j], 0, 0, 0);
                acc[i][j] = __builtin_amdgcn_mfma_f32_16x16x32_bf16(al[i], wh[j], acc[i][j], 0, 0, 0);
            }
        __syncthreads();
    }

#pragma unroll
    for (int j = 0; j < JN; ++j) {
        const int col = col0 + wn + j * 16 + r15;
        const float bb = bias[col];
#pragma unroll
        for (int i = 0; i < 4; ++i) {
            const int rowb = row0 + wm + i * 16 + (lane >> 4) * 4;
#pragma unroll
            for (int r = 0; r < 4; ++r) {
                float v = acc[i][j][r] + bb;
                if (act) v = v > 0.f ? v : 0.2f * v;
                const size_t idx = (size_t)(rowb + r) * N + col;
                if (Cp) Cp[idx] = packf(v);
                else    Chi[idx] = f2b(v);
            }
        }
    }
}

// ---------------- weight fp32 -> hi (and optional lo) bf16 planes ----------------
__global__ void wconv(const float* __restrict__ wsrc, u16* __restrict__ hi,
                      u16* __restrict__ lo, int n)
{
    int i = blockIdx.x * 256 + threadIdx.x;
    if (i < n) {
        float v = wsrc[i];
        u16 h = f2b(v);
        hi[i] = h;
        if (lo) lo[i] = f2b(v - b2f(h));
    }
}

// ---------------- fp32 vector GEMM (node projections only) ----------------
__global__ __launch_bounds__(256)
void gemm_awt(const float* __restrict__ A, const float* __restrict__ W,
              const float* __restrict__ bias, float* __restrict__ C,
              int M, int N, int K)
{
    __shared__ float As[BK][BM + 4];
    __shared__ float Ws[BK][BN + 4];
    const int tid  = threadIdx.x;
    const int row0 = blockIdx.x * BM;
    const int col0 = blockIdx.y * BN;
    const int tr = tid & 15;
    const int tc = tid >> 4;
    const int lr = tid >> 2;
    const int lk = (tid & 3) * 4;

    float acc[4][4] = {{0.f, 0.f, 0.f, 0.f}};

    for (int k0 = 0; k0 < K; k0 += BK) {
        {
            int gr = row0 + lr;
            float4 v = make_float4(0.f, 0.f, 0.f, 0.f);
            if (gr < M) v = *(const float4*)(A + (size_t)gr * K + k0 + lk);
            As[lk + 0][lr] = v.x; As[lk + 1][lr] = v.y;
            As[lk + 2][lr] = v.z; As[lk + 3][lr] = v.w;
            int gn = col0 + lr;
            float4 ww = *(const float4*)(W + (size_t)gn * K + k0 + lk);
            Ws[lk + 0][lr] = ww.x; Ws[lk + 1][lr] = ww.y;
            Ws[lk + 2][lr] = ww.z; Ws[lk + 3][lr] = ww.w;
        }
        __syncthreads();
#pragma unroll
        for (int kk = 0; kk < BK; ++kk) {
            float4 af = *(const float4*)&As[kk][tr * 4];
            float4 wf = *(const float4*)&Ws[kk][tc * 4];
            float a4[4] = {af.x, af.y, af.z, af.w};
            float w4[4] = {wf.x, wf.y, wf.z, wf.w};
#pragma unroll
            for (int i = 0; i < 4; ++i)
#pragma unroll
                for (int j = 0; j < 4; ++j) acc[i][j] += a4[i] * w4[j];
        }
        __syncthreads();
    }
#pragma unroll
    for (int i = 0; i < 4; ++i) {
        int r = row0 + tr * 4 + i;
        if (r >= M) continue;
        float o[4];
#pragma unroll
        for (int j = 0; j < 4; ++j) o[j] = acc[i][j] + bias[col0 + tc * 4 + j];
        *(float4*)(C + (size_t)r * N + col0 + tc * 4) =
            make_float4(o[0], o[1], o[2], o[3]);
    }
}

// ---------------- segment-softmax ----------------
__global__ void seg_init(u32* __restrict__ amax, float* __restrict__ denom, int n)
{
    int i = blockIdx.x * 256 + threadIdx.x;
    if (i < n) { amax[i] = 0u; denom[i] = 0.f; }
}

template<typename TQ, int MODE>
__global__ __launch_bounds__(256)
void attn_alpha(const int* __restrict__ src, const int* __restrict__ dst,
                const TQ* __restrict__ qn, const float* __restrict__ kn,
                float* __restrict__ alpha, u32* __restrict__ amax, int E)
{
    int e = blockIdx.x * 4 + (threadIdx.x >> 6);
    int lane = threadIdx.x & 63;
    if (e >= E) return;
    int s = src[e], d = dst[e];
    const TQ* qp = MODE ? (qn + (size_t)e * D) : (qn + (size_t)d * D);
    const float* kp = kn + (size_t)s * D;
    float dot = 0.f;
#pragma unroll
    for (int j = 0; j < 4; ++j)
        dot += ld1(qp + lane * 4 + j) * kp[lane * 4 + j];
    dot = wred(dot);
    if (lane == 0) {
        alpha[e] = dot;
        atomicMax(amax + d, f2ord(dot));
    }
}

__global__ void seg_exp(const int* __restrict__ dst, const float* __restrict__ alpha,
                        const u32* __restrict__ amax, float* __restrict__ ebuf,
                        float* __restrict__ denom, int E)
{
    int e = blockIdx.x * 256 + threadIdx.x;
    if (e >= E) return;
    int d = dst[e];
    float ex = expf(alpha[e] - ord2f(amax[d]));
    ebuf[e] = ex;
    atomicAdd(denom + d, ex);
}

// ---------------- out(local, packed) = LN(q + attn*v[src]) ----------------
template<typename TQ, int MODE>
__global__ __launch_bounds__(256)
void attn_out_ln(const int* __restrict__ src, const int* __restrict__ dst,
                 const TQ* __restrict__ qn, const float* __restrict__ vn,
                 const float* __restrict__ ebuf, const float* __restrict__ denom,
                 const float* __restrict__ g, const float* __restrict__ bb,
                 u32* __restrict__ outp, int e0, int cm)
{
    int le = blockIdx.x * 4 + (threadIdx.x >> 6);
    int lane = threadIdx.x & 63;
    if (le >= cm) return;
    int ge = e0 + le;
    int s = src[ge], d = dst[ge];
    float attn = ebuf[ge] / denom[d];
    const TQ* qp = MODE ? (qn + (size_t)ge * D) : (qn + (size_t)d * D);
    const float* vp = vn + (size_t)s * D;
    int d0 = lane * 4;
    float a0 = ld1(qp + d0 + 0) + attn * vp[d0 + 0];
    float a1 = ld1(qp + d0 + 1) + attn * vp[d0 + 1];
    float a2 = ld1(qp + d0 + 2) + attn * vp[d0 + 2];
    float a3 = ld1(qp + d0 + 3) + attn * vp[d0 + 3];
    float mean = wred(a0 + a1 + a2 + a3) * (1.f / D);
    float c0 = a0 - mean, c1 = a1 - mean, c2 = a2 - mean, c3 = a3 - mean;
    float var = wred(c0 * c0 + c1 * c1 + c2 * c2 + c3 * c3) * (1.f / D);
    float rstd = rsqrtf(var + 1e-5f);
    uint4 p;
    p.x = packf(c0 * rstd * g[d0 + 0] + bb[d0 + 0]);
    p.y = packf(c1 * rstd * g[d0 + 1] + bb[d0 + 1]);
    p.z = packf(c2 * rstd * g[d0 + 2] + bb[d0 + 2]);
    p.w = packf(c3 * rstd * g[d0 + 3] + bb[d0 + 3]);
    *(uint4*)(outp + (size_t)le * D + d0) = p;
}

// ---------------- y = LN(lrelu(x)), packed u32 -> bf16 u16 ----------------
__global__ __launch_bounds__(256)
void lrelu_ln(const u32* __restrict__ inp, const float* __restrict__ g,
              const float* __restrict__ bb, u16* __restrict__ out, int cm)
{
    int le = blockIdx.x * 4 + (threadIdx.x >> 6);
    int lane = threadIdx.x & 63;
    if (le >= cm) return;
    size_t base = (size_t)le * D + lane * 4;
    uint4 xp = *(const uint4*)(inp + base);
    float x0 = unpackf(xp.x), x1 = unpackf(xp.y);
    float x2 = unpackf(xp.z), x3 = unpackf(xp.w);
    float a0 = x0 > 0.f ? x0 : 0.2f * x0;
    float a1 = x1 > 0.f ? x1 : 0.2f * x1;
    float a2 = x2 > 0.f ? x2 : 0.2f * x2;
    float a3 = x3 > 0.f ? x3 : 0.2f * x3;
    float mean = wred(a0 + a1 + a2 + a3) * (1.f / D);
    float c0 = a0 - mean, c1 = a1 - mean, c2 = a2 - mean, c3 = a3 - mean;
    float var = wred(c0 * c0 + c1 * c1 + c2 * c2 + c3 * c3) * (1.f / D);
    float rstd = rsqrtf(var + 1e-5f);
    int d0 = lane * 4;
    ushort4 o;
    o.x = f2b(c0 * rstd * g[d0 + 0] + bb[d0 + 0]);
    o.y = f2b(c1 * rstd * g[d0 + 1] + bb[d0 + 1]);
    o.z = f2b(c2 * rstd * g[d0 + 2] + bb[d0 + 2]);
    o.w = f2b(c3 * rstd * g[d0 + 3] + bb[d0 + 3]);
    *(ushort4*)(out + base) = o;
}

// ---------------- out[e0+le] = dot(LN(h+q), Wvec) + bvec (u16 h, u16 q) ----------------
__global__ __launch_bounds__(256)
void final_k(const u16* __restrict__ hp, const u16* __restrict__ qp,
             const float* __restrict__ gfin, const float* __restrict__ bfin,
             const float* __restrict__ wvec, const float* __restrict__ bvec,
             float* __restrict__ out, int e0, int cm)
{
    int le = blockIdx.x * 4 + (threadIdx.x >> 6);
    int lane = threadIdx.x & 63;
    if (le >= cm) return;
    size_t base = (size_t)le * D + lane * 4;
    ushort4 hv = *(const ushort4*)(hp + base);
    ushort4 qv = *(const ushort4*)(qp + base);
    float a0 = b2f(hv.x) + b2f(qv.x);
    float a1 = b2f(hv.y) + b2f(qv.y);
    float a2 = b2f(hv.z) + b2f(qv.z);
    float a3 = b2f(hv.w) + b2f(qv.w);
    float mean = wred(a0 + a1 + a2 + a3) * (1.f / D);
    float c0 = a0 - mean, c1 = a1 - mean, c2 = a2 - mean, c3 = a3 - mean;
    float var = wred(c0 * c0 + c1 * c1 + c2 * c2 + c3 * c3) * (1.f / D);
    float rstd = rsqrtf(var + 1e-5f);
    int d0 = lane * 4;
    float t0 = c0 * rstd * gfin[d0 + 0] + bfin[d0 + 0];
    float t1 = c1 * rstd * gfin[d0 + 1] + bfin[d0 + 1];
    float t2 = c2 * rstd * gfin[d0 + 2] + bfin[d0 + 2];
    float t3 = c3 * rstd * gfin[d0 + 3] + bfin[d0 + 3];
    float part = t0 * wvec[d0 + 0] + t1 * wvec[d0 + 1] +
                 t2 * wvec[d0 + 2] + t3 * wvec[d0 + 3];
    part = wred(part);
    if (lane == 0) out[e0 + le] = part + bvec[0];
}

extern "C" void kernel_launch(void* const* d_in, const int* in_sizes, int n_in,
                              void* d_out, int out_size, void* d_ws, size_t ws_size,
                              hipStream_t stream)
{
    const int*   ei   = (const int*)d_in[0];
    const float* x    = (const float*)d_in[1];
    const float* Wq   = (const float*)d_in[2];
    const float* bq   = (const float*)d_in[3];
    const float* Wk   = (const float*)d_in[4];
    const float* bk   = (const float*)d_in[5];
    const float* Wv   = (const float*)d_in[6];
    const float* bv   = (const float*)d_in[7];
    const float* Wff  = (const float*)d_in[8];
    const float* bff  = (const float*)d_in[9];
    const float* ga   = (const float*)d_in[10];
    const float* ba   = (const float*)d_in[11];
    const float* gf   = (const float*)d_in[12];
    const float* bf   = (const float*)d_in[13];
    const float* gfin = (const float*)d_in[14];
    const float* bfin = (const float*)d_in[15];
    const float* W3   = (const float*)d_in[16];
    const float* b3   = (const float*)d_in[17];
    const float* W4   = (const float*)d_in[18];
    const float* b4   = (const float*)d_in[19];
    const float* W5   = (const float*)d_in[20];
    const float* b5   = (const float*)d_in[21];
    const float* Wvec = (const float*)d_in[22];
    const float* bvec = (const float*)d_in[23];

    const int E  = in_sizes[0] / 2;     // 160000 (=1250*128)
    const int Nn = in_sizes[1] / D;
    const int* src = ei;
    const int* dst = ei + E;

    // ---- workspace carve: fixed region ----
    char* base = (char*)d_ws;
    size_t off = 0;
    auto take = [&](size_t bytes) -> void* {
        off = (off + 255) & ~(size_t)255;
        void* r = base + off;
        off += bytes;
        return r;
    };
    float* nK1 = (float*)take((size_t)Nn * D * 4);
    float* nV1 = (float*)take((size_t)Nn * D * 4);
    u16*   q1  = (u16*)take((size_t)E * D * 2);          // hi-only bf16
    float* alpha = (float*)take((size_t)E * 4);
    float* ebuf  = (float*)take((size_t)E * 4);
    u32*   amax  = (u32*)take((size_t)Nn * 4);
    float* denom = (float*)take((size_t)Nn * 4);
    u16* wff0h = (u16*)take((size_t)D * D * 2); u16* wff0l = (u16*)take((size_t)D * D * 2);
    u16* wff1h = (u16*)take((size_t)D * D * 2); u16* wff1l = (u16*)take((size_t)D * D * 2);
    u16* wq1h  = (u16*)take((size_t)D * D * 2); u16* wq1l  = (u16*)take((size_t)D * D * 2);
    u16* w3h = (u16*)take((size_t)3 * D * D * 2);
    u16* w4h = (u16*)take((size_t)9 * D * D * 2);
    u16* w5h = (u16*)take((size_t)3 * D * D * 2);

    // ---- adaptive chunk: area = c1p(CM*1024) + c2p(CM*1024) + zone ----
    const size_t nodeB = (size_t)3 * Nn * D * 4;
    size_t rem = ws_size > off + 8192 ? ws_size - off - 8192 : 0;
    size_t cmA = rem / 4096;
    size_t cmB = rem > nodeB ? (rem - nodeB) / 2048 : 0;
    size_t CMs = (cmA * 2048 >= nodeB) ? cmA : cmB;
    CMs = (CMs / 128) * 128;
    if (CMs > (size_t)E) CMs = E;
    if (CMs < 128) CMs = 128;
    const int CM = (int)CMs;

    u32* c1p = (u32*)take((size_t)CM * D * 4);
    u32* c2p = (u32*)take((size_t)CM * D * 4);
    size_t zoneB = (size_t)CM * 2048 > nodeB ? (size_t)CM * 2048 : nodeB;
    char* zone = (char*)take(zoneB);
    u16* c2n = (u16*)zone;                                // CM*D u16
    u16* c3  = (u16*)(zone + (size_t)CM * D * 2);         // CM*3D u16
    float* nQ0 = (float*)zone;                            // pass-0/1 only
    float* nK0 = nQ0 + (size_t)Nn * D;
    float* nV0 = nK0 + (size_t)Nn * D;
    u16* c4 = (u16*)c1p;                                  // CM*3D u16
    u16* c5 = (u16*)((char*)c1p + (size_t)CM * 3 * D * 2);// CM*D u16

    dim3 blk(256);
    dim3 blk2(512);
    dim3 gNode((Nn + BM - 1) / BM, D / BN);
    int gridSeg = (Nn + 255) / 256;
    int gridE4  = (E + 3) / 4;
    int gridE   = (E + 255) / 256;

    // ---- weight conversion ----
    wconv<<<(D * D + 255) / 256, 256, 0, stream>>>(Wff,          wff0h, wff0l, D * D);
    wconv<<<(D * D + 255) / 256, 256, 0, stream>>>(Wff + D * D,  wff1h, wff1l, D * D);
    wconv<<<(D * D + 255) / 256, 256, 0, stream>>>(Wq + D * D,   wq1h,  wq1l,  D * D);
    wconv<<<(3 * D * D + 255) / 256, 256, 0, stream>>>(W3, w3h, (u16*)nullptr, 3 * D * D);
    wconv<<<(9 * D * D + 255) / 256, 256, 0, stream>>>(W4, w4h, (u16*)nullptr, 9 * D * D);
    wconv<<<(3 * D * D + 255) / 256, 256, 0, stream>>>(W5, w5h, (u16*)nullptr, 3 * D * D);

    // ---- node projections (fp32 vector GEMM) ----
    gemm_awt<<<gNode, blk, 0, stream>>>(x, Wq,         bq,     nQ0, Nn, D, D);
    gemm_awt<<<gNode, blk, 0, stream>>>(x, Wk,         bk,     nK0, Nn, D, D);
    gemm_awt<<<gNode, blk, 0, stream>>>(x, Wv,         bv,     nV0, Nn, D, D);
    gemm_awt<<<gNode, blk, 0, stream>>>(x, Wk + D * D, bk + D, nK1, Nn, D, D);
    gemm_awt<<<gNode, blk, 0, stream>>>(x, Wv + D * D, bv + D, nV1, Nn, D, D);

    // ---- layer-0 segment softmax (fp32 exact) ----
    seg_init<<<gridSeg, 256, 0, stream>>>(amax, denom, Nn);
    attn_alpha<float, 0><<<gridE4, blk, 0, stream>>>(src, dst, nQ0, nK0, alpha, amax, E);
    seg_exp<<<gridE, 256, 0, stream>>>(dst, alpha, amax, ebuf, denom, E);

    // ---- pass 1 (chunked): attnLN0 -> Wff0 -> Wq1 -> q1 (bf16 hi) ----
    for (int e0 = 0; e0 < E; e0 += CM) {
        int cm = E - e0 < CM ? E - e0 : CM;
        int gE4 = (cm + 3) / 4;
        dim3 gD(cm / 128, D / 64);
        attn_out_ln<float, 0><<<gE4, blk, 0, stream>>>(src, dst, nQ0, nV0, ebuf, denom,
                                                       ga, ba, c1p, e0, cm);
        gemm3<<<gD, blk, 0, stream>>>(c1p, wff0h, wff0l, bff,
                                      c2p, (u16*)nullptr, cm, D, D, 0);
        gemm3<<<gD, blk, 0, stream>>>(c2p, wq1h, wq1l, bq + D,
                                      (u32*)nullptr, q1 + (size_t)e0 * D,
                                      cm, D, D, 0);
    }

    // ---- layer-1 segment softmax ----
    seg_init<<<gridSeg, 256, 0, stream>>>(amax, denom, Nn);
    attn_alpha<u16, 1><<<gridE4, blk, 0, stream>>>(src, dst, q1, nK1, alpha, amax, E);
    seg_exp<<<gridE, 256, 0, stream>>>(dst, alpha, amax, ebuf, denom, E);

    // ---- pass 2 (chunked) ----
    for (int e0 = 0; e0 < E; e0 += CM) {
        int cm = E - e0 < CM ? E - e0 : CM;
        int gE4 = (cm + 3) / 4;
        dim3 gD(cm / 128, D / 64);
        dim3 g2a(cm / 128, (3 * D) / 256);   // 128x256 tiles, 3 col sweeps
        dim3 g2b(cm / 128, D / 256);         // 1 col sweep
        attn_out_ln<u16, 1><<<gE4, blk, 0, stream>>>(src, dst, q1, nV1, ebuf, denom,
                                                     ga + D, ba + D, c1p, e0, cm);
        gemm3<<<gD, blk, 0, stream>>>(c1p, wff1h, wff1l, bff + D,
                                      c2p, (u16*)nullptr, cm, D, D, 0);
        lrelu_ln<<<gE4, blk, 0, stream>>>(c2p, gf, bf, c2n, cm);
        gemm2<1><<<g2a, blk2, 0, stream>>>(c2n, w3h, b3, c3, cm, 3 * D, D);
        gemm2<1><<<g2a, blk2, 0, stream>>>(c3, w4h, b4, c4, cm, 3 * D, 3 * D);
        gemm2<0><<<g2b, blk2, 0, stream>>>(c4, w5h, b5, c5, cm, D, 3 * D);
        final_k<<<gE4, blk, 0, stream>>>(c5, c2n, gfin, bfin, Wvec, bvec,
                                         (float*)d_out, e0, cm);
    }
}

// Round 12
// 1583.947 us; speedup vs baseline: 1.0712x; 1.0712x over previous
//
#include <hip/hip_runtime.h>

#define D 256
#define BM 64
#define BN 64
#define BK 16

typedef unsigned short u16;
typedef unsigned int u32;
typedef __attribute__((ext_vector_type(8))) short short8;
typedef __attribute__((ext_vector_type(4))) float f32x4;
typedef __attribute__((ext_vector_type(16))) float f32x16;

// ---------------- bf16 <-> f32, split-pack ----------------
__device__ __forceinline__ float b2f(u16 u) {
    return __uint_as_float(((u32)u) << 16);
}
__device__ __forceinline__ u16 f2b(float f) {
    u32 u = __float_as_uint(f);
    return (u16)((u + 0x7FFFu + ((u >> 16) & 1u)) >> 16);  // RNE
}
__device__ __forceinline__ u32 packf(float v) {
    u16 h = f2b(v);
    u16 l = f2b(v - b2f(h));
    return ((u32)h << 16) | l;
}
__device__ __forceinline__ float unpackf(u32 p) {
    return b2f((u16)(p >> 16)) + b2f((u16)(p & 0xffffu));
}
template<typename T> __device__ __forceinline__ float ld1(const T* p);
template<> __device__ __forceinline__ float ld1<float>(const float* p) { return *p; }
template<> __device__ __forceinline__ float ld1<u16>(const u16* p) { return b2f(*p); }

// ---------------- ordered-uint float atomic max ----------------
__device__ __forceinline__ u32 f2ord(float f) {
    u32 b = __float_as_uint(f);
    return (b & 0x80000000u) ? ~b : (b | 0x80000000u);
}
__device__ __forceinline__ float ord2f(u32 u) {
    return (u & 0x80000000u) ? __uint_as_float(u & 0x7fffffffu)
                             : __uint_as_float(~u);
}

__device__ __forceinline__ float wred(float v) {
#pragma unroll
    for (int m = 32; m; m >>= 1) v += __shfl_xor(v, m);
    return v;
}

// async global(16B/lane) -> LDS (wave-uniform base + lane*16)
__device__ __forceinline__ void gl_lds16(const u16* g, u16* l) {
    __builtin_amdgcn_global_load_lds(
        (__attribute__((address_space(1))) void*)(u16*)g,
        (__attribute__((address_space(3))) void*)l, 16, 0, 0);
}

// ======== gemm2: single-term (hi-only W) MFMA GEMM (head MLP) ========
// C = act(A[M,K] @ W[N,K]^T + b). A bf16 u16; W hi-plane u16.
// 512 threads: block tile 128x256, wave grid 2x4, wave tile 64x64.
// 32x32x16 MFMA. M%128==0, N%256==0, K%32==0. Scalar u16 epilogue
// (R9 replay-proven form; transpose epilogue regressed — R10 post-mortem).
template<int ACT>
__global__ __launch_bounds__(512, 4)
void gemm2(const u16* __restrict__ A, const u16* __restrict__ Whi,
           const float* __restrict__ bias, u16* __restrict__ C,
           int M, int N, int K)
{
    __shared__ u16 sA[128 * 32];       // 8 KB
    __shared__ u16 sWh[256 * 32];      // 16 KB

    const int tid  = threadIdx.x;
    const int lane = tid & 63;
    const int w    = tid >> 6;             // wave 0..7
    const int wm   = (w & 1) * 64;         // wave row-origin (0/64)
    const int wn   = (w >> 1) * 64;        // wave col-origin (0/64/128/192)
    const int row0 = blockIdx.x * 128;
    const int col0 = blockIdx.y * 256;

    f32x16 acc[2][2];
#pragma unroll
    for (int i = 0; i < 2; ++i)
#pragma unroll
        for (int j = 0; j < 2; ++j)
#pragma unroll
            for (int r = 0; r < 16; ++r) acc[i][j][r] = 0.f;

    const int r31   = lane & 31;
    const int khalf = lane >> 5;
    const int skey  = (r31 >> 1) & 3;
    const int lrow = lane >> 2;
    const int gck  = (lane & 3) ^ ((lane >> 3) & 3);

    for (int k0 = 0; k0 < K; k0 += 32) {
#pragma unroll
        for (int s = 0; s < 2; ++s) {
            const int rbase = w * 32 + s * 16;          // wave-uniform
            const size_t gW = (size_t)(col0 + rbase + lrow) * K + k0 + gck * 8;
            gl_lds16(Whi + gW, sWh + rbase * 32);
        }
        {
            const int ar = tid >> 2;
            const int c = tid & 3;
            uint4 pk = *(const uint4*)(A + (size_t)(row0 + ar) * K + k0 + c * 8);
            const int slot = c ^ ((ar >> 1) & 3);
            *(uint4*)(sA + ar * 32 + slot * 8) = pk;
        }
        __syncthreads();

        short8 af[2][2], wfh[2][2];
#pragma unroll
        for (int i = 0; i < 2; ++i)
#pragma unroll
            for (int q = 0; q < 2; ++q) {
                const int slot = (q * 2 + khalf) ^ skey;
                af[i][q] = *(const short8*)(sA + (wm + i * 32 + r31) * 32 + slot * 8);
                wfh[i][q] = *(const short8*)(sWh + (wn + i * 32 + r31) * 32 + slot * 8);
            }
#pragma unroll
        for (int i = 0; i < 2; ++i)
#pragma unroll
            for (int j = 0; j < 2; ++j)
#pragma unroll
                for (int q = 0; q < 2; ++q)
                    acc[i][j] = __builtin_amdgcn_mfma_f32_32x32x16_bf16(af[i][q], wfh[j][q], acc[i][j], 0, 0, 0);
        __syncthreads();
    }

    // epilogue: scalar stores. C/D: col=lane&31, row=(reg&3)+8*(reg>>2)+4*khalf
#pragma unroll
    for (int j = 0; j < 2; ++j) {
        const int col = col0 + wn + j * 32 + r31;
        const float bb = bias[col];
#pragma unroll
        for (int i = 0; i < 2; ++i) {
            const int rowb = row0 + wm + i * 32 + 4 * khalf;
#pragma unroll
            for (int reg = 0; reg < 16; ++reg) {
                const int row = rowb + (reg & 3) + 8 * (reg >> 2);
                float v = acc[i][j][reg] + bb;
                if (ACT) v = v > 0.f ? v : 0.2f * v;
                C[(size_t)row * N + col] = f2b(v);
            }
        }
    }
}

// ======== gemm3w: 3-term split MFMA GEMM, N=256 single-sweep ========
// A packed u32 (hi<<16|lo). W hi/lo planes. 16x16x32.
// 512 threads: block 128x256 (full N), wave grid 2x4, wave tile 64x64.
// Same per-tile MFMA sequence as previous gemm3 -> bit-identical numerics.
// Output: Cp packed u32, or Chi hi-only u16 (if Cp null).
__global__ __launch_bounds__(512, 4)
void gemm3w(const u32* __restrict__ Ap,
            const u16* __restrict__ Whi, const u16* __restrict__ Wlo,
            const float* __restrict__ bias,
            u32* __restrict__ Cp, u16* __restrict__ Chi,
            int M, int K, int act)
{
    constexpr int N = 256;
    __shared__ u16 sAhi[128 * 32];     // 8 KB
    __shared__ u16 sAlo[128 * 32];     // 8 KB
    __shared__ u16 sWhi[256 * 32];     // 16 KB
    __shared__ u16 sWlo[256 * 32];     // 16 KB

    const int tid  = threadIdx.x;
    const int lane = tid & 63;
    const int w    = tid >> 6;             // 0..7
    const int wm   = (w & 1) * 64;
    const int wn   = (w >> 1) * 64;        // 0/64/128/192
    const int row0 = blockIdx.x * 128;

    f32x4 acc[4][4];
#pragma unroll
    for (int i = 0; i < 4; ++i)
#pragma unroll
        for (int j = 0; j < 4; ++j) acc[i][j] = (f32x4){0.f, 0.f, 0.f, 0.f};

    const int lrow = lane >> 2;
    const int gck  = (lane & 3) ^ ((lane >> 3) & 3);
    const int r15 = lane & 15;
    const int rck = ((lane >> 4) ^ ((r15 >> 1) & 3)) * 8;

    for (int k0 = 0; k0 < K; k0 += 32) {
        // stage W: 256 rows both planes; 8 waves x 2 segs x 16 rows
#pragma unroll
        for (int s = 0; s < 2; ++s) {
            const int rbase = w * 32 + s * 16;          // wave-uniform
            const size_t gW = (size_t)(rbase + lrow) * K + k0 + gck * 8;
            gl_lds16(Whi + gW, sWhi + rbase * 32);
            gl_lds16(Wlo + gW, sWlo + rbase * 32);
        }
        // stage A (packed -> split): 128x32 u32 = 16 KB, 2 x uint4/thread
#pragma unroll
        for (int it = 0; it < 2; ++it) {
            const int u = tid + it * 512;
            const int ar = u >> 3;
            const int pos = u & 7;
            uint4 pk = *(const uint4*)(Ap + (size_t)(row0 + ar) * K + k0 + pos * 4);
            const int slot = (pos >> 1) ^ ((ar >> 1) & 3);
            const int base = ar * 32 + slot * 8 + (pos & 1) * 4;
            ushort4 h4, l4;
            h4.x = (u16)(pk.x >> 16); l4.x = (u16)(pk.x & 0xffffu);
            h4.y = (u16)(pk.y >> 16); l4.y = (u16)(pk.y & 0xffffu);
            h4.z = (u16)(pk.z >> 16); l4.z = (u16)(pk.z & 0xffffu);
            h4.w = (u16)(pk.w >> 16); l4.w = (u16)(pk.w & 0xffffu);
            *(ushort4*)(sAhi + base) = h4;
            *(ushort4*)(sAlo + base) = l4;
        }
        __syncthreads();

        short8 ah[4], al[4], wh[4], wl[4];
#pragma unroll
        for (int i = 0; i < 4; ++i) {
            const int offA = (wm + i * 16 + r15) * 32 + rck;
            ah[i] = *(const short8*)(sAhi + offA);
            al[i] = *(const short8*)(sAlo + offA);
        }
#pragma unroll
        for (int j = 0; j < 4; ++j) {
            const int offW = (wn + j * 16 + r15) * 32 + rck;
            wh[j] = *(const short8*)(sWhi + offW);
            wl[j] = *(const short8*)(sWlo + offW);
        }
#pragma unroll
        for (int i = 0; i < 4; ++i)
#pragma unroll
            for (int j = 0; j < 4; ++j) {
                acc[i][j] = __builtin_amdgcn_mfma_f32_16x16x32_bf16(ah[i], wh[j], acc[i][j], 0, 0, 0);
                acc[i][j] = __builtin_amdgcn_mfma_f32_16x16x32_bf16(ah[i], wl[j], acc[i][j], 0, 0, 0);
                acc[i][j] = __builtin_amdgcn_mfma_f32_16x16x32_bf16(al[i], wh[j], acc[i][j], 0, 0, 0);
            }
        __syncthreads();
    }

#pragma unroll
    for (int j = 0; j < 4; ++j) {
        const int col = wn + j * 16 + r15;
        const float bb = bias[col];
#pragma unroll
        for (int i = 0; i < 4; ++i) {
            const int rowb = row0 + wm + i * 16 + (lane >> 4) * 4;
#pragma unroll
            for (int r = 0; r < 4; ++r) {
                float v = acc[i][j][r] + bb;
                if (act) v = v > 0.f ? v : 0.2f * v;
                const size_t idx = (size_t)(rowb + r) * N + col;
                if (Cp) Cp[idx] = packf(v);
                else    Chi[idx] = f2b(v);
            }
        }
    }
}

// ---------------- weight fp32 -> hi (and optional lo) bf16 planes ----------------
__global__ void wconv(const float* __restrict__ wsrc, u16* __restrict__ hi,
                      u16* __restrict__ lo, int n)
{
    int i = blockIdx.x * 256 + threadIdx.x;
    if (i < n) {
        float v = wsrc[i];
        u16 h = f2b(v);
        hi[i] = h;
        if (lo) lo[i] = f2b(v - b2f(h));
    }
}

// ---------------- fp32 vector GEMM (node projections only) ----------------
__global__ __launch_bounds__(256)
void gemm_awt(const float* __restrict__ A, const float* __restrict__ W,
              const float* __restrict__ bias, float* __restrict__ C,
              int M, int N, int K)
{
    __shared__ float As[BK][BM + 4];
    __shared__ float Ws[BK][BN + 4];
    const int tid  = threadIdx.x;
    const int row0 = blockIdx.x * BM;
    const int col0 = blockIdx.y * BN;
    const int tr = tid & 15;
    const int tc = tid >> 4;
    const int lr = tid >> 2;
    const int lk = (tid & 3) * 4;

    float acc[4][4] = {{0.f, 0.f, 0.f, 0.f}};

    for (int k0 = 0; k0 < K; k0 += BK) {
        {
            int gr = row0 + lr;
            float4 v = make_float4(0.f, 0.f, 0.f, 0.f);
            if (gr < M) v = *(const float4*)(A + (size_t)gr * K + k0 + lk);
            As[lk + 0][lr] = v.x; As[lk + 1][lr] = v.y;
            As[lk + 2][lr] = v.z; As[lk + 3][lr] = v.w;
            int gn = col0 + lr;
            float4 ww = *(const float4*)(W + (size_t)gn * K + k0 + lk);
            Ws[lk + 0][lr] = ww.x; Ws[lk + 1][lr] = ww.y;
            Ws[lk + 2][lr] = ww.z; Ws[lk + 3][lr] = ww.w;
        }
        __syncthreads();
#pragma unroll
        for (int kk = 0; kk < BK; ++kk) {
            float4 af = *(const float4*)&As[kk][tr * 4];
            float4 wf = *(const float4*)&Ws[kk][tc * 4];
            float a4[4] = {af.x, af.y, af.z, af.w};
            float w4[4] = {wf.x, wf.y, wf.z, wf.w};
#pragma unroll
            for (int i = 0; i < 4; ++i)
#pragma unroll
                for (int j = 0; j < 4; ++j) acc[i][j] += a4[i] * w4[j];
        }
        __syncthreads();
    }
#pragma unroll
    for (int i = 0; i < 4; ++i) {
        int r = row0 + tr * 4 + i;
        if (r >= M) continue;
        float o[4];
#pragma unroll
        for (int j = 0; j < 4; ++j) o[j] = acc[i][j] + bias[col0 + tc * 4 + j];
        *(float4*)(C + (size_t)r * N + col0 + tc * 4) =
            make_float4(o[0], o[1], o[2], o[3]);
    }
}

// ---------------- segment-softmax ----------------
__global__ void seg_init(u32* __restrict__ amax, float* __restrict__ denom, int n)
{
    int i = blockIdx.x * 256 + threadIdx.x;
    if (i < n) { amax[i] = 0u; denom[i] = 0.f; }
}

template<typename TQ, int MODE>
__global__ __launch_bounds__(256)
void attn_alpha(const int* __restrict__ src, const int* __restrict__ dst,
                const TQ* __restrict__ qn, const float* __restrict__ kn,
                float* __restrict__ alpha, u32* __restrict__ amax, int E)
{
    int e = blockIdx.x * 4 + (threadIdx.x >> 6);
    int lane = threadIdx.x & 63;
    if (e >= E) return;
    int s = src[e], d = dst[e];
    const TQ* qp = MODE ? (qn + (size_t)e * D) : (qn + (size_t)d * D);
    const float* kp = kn + (size_t)s * D;
    float dot = 0.f;
#pragma unroll
    for (int j = 0; j < 4; ++j)
        dot += ld1(qp + lane * 4 + j) * kp[lane * 4 + j];
    dot = wred(dot);
    if (lane == 0) {
        alpha[e] = dot;
        atomicMax(amax + d, f2ord(dot));
    }
}

__global__ void seg_exp(const int* __restrict__ dst, const float* __restrict__ alpha,
                        const u32* __restrict__ amax, float* __restrict__ ebuf,
                        float* __restrict__ denom, int E)
{
    int e = blockIdx.x * 256 + threadIdx.x;
    if (e >= E) return;
    int d = dst[e];
    float ex = expf(alpha[e] - ord2f(amax[d]));
    ebuf[e] = ex;
    atomicAdd(denom + d, ex);
}

// ---------------- out(local, packed) = LN(q + attn*v[src]) ----------------
template<typename TQ, int MODE>
__global__ __launch_bounds__(256)
void attn_out_ln(const int* __restrict__ src, const int* __restrict__ dst,
                 const TQ* __restrict__ qn, const float* __restrict__ vn,
                 const float* __restrict__ ebuf, const float* __restrict__ denom,
                 const float* __restrict__ g, const float* __restrict__ bb,
                 u32* __restrict__ outp, int e0, int cm)
{
    int le = blockIdx.x * 4 + (threadIdx.x >> 6);
    int lane = threadIdx.x & 63;
    if (le >= cm) return;
    int ge = e0 + le;
    int s = src[ge], d = dst[ge];
    float attn = ebuf[ge] / denom[d];
    const TQ* qp = MODE ? (qn + (size_t)ge * D) : (qn + (size_t)d * D);
    const float* vp = vn + (size_t)s * D;
    int d0 = lane * 4;
    float a0 = ld1(qp + d0 + 0) + attn * vp[d0 + 0];
    float a1 = ld1(qp + d0 + 1) + attn * vp[d0 + 1];
    float a2 = ld1(qp + d0 + 2) + attn * vp[d0 + 2];
    float a3 = ld1(qp + d0 + 3) + attn * vp[d0 + 3];
    float mean = wred(a0 + a1 + a2 + a3) * (1.f / D);
    float c0 = a0 - mean, c1 = a1 - mean, c2 = a2 - mean, c3 = a3 - mean;
    float var = wred(c0 * c0 + c1 * c1 + c2 * c2 + c3 * c3) * (1.f / D);
    float rstd = rsqrtf(var + 1e-5f);
    uint4 p;
    p.x = packf(c0 * rstd * g[d0 + 0] + bb[d0 + 0]);
    p.y = packf(c1 * rstd * g[d0 + 1] + bb[d0 + 1]);
    p.z = packf(c2 * rstd * g[d0 + 2] + bb[d0 + 2]);
    p.w = packf(c3 * rstd * g[d0 + 3] + bb[d0 + 3]);
    *(uint4*)(outp + (size_t)le * D + d0) = p;
}

// ---------------- y = LN(lrelu(x)), packed u32 -> bf16 u16 ----------------
__global__ __launch_bounds__(256)
void lrelu_ln(const u32* __restrict__ inp, const float* __restrict__ g,
              const float* __restrict__ bb, u16* __restrict__ out, int cm)
{
    int le = blockIdx.x * 4 + (threadIdx.x >> 6);
    int lane = threadIdx.x & 63;
    if (le >= cm) return;
    size_t base = (size_t)le * D + lane * 4;
    uint4 xp = *(const uint4*)(inp + base);
    float x0 = unpackf(xp.x), x1 = unpackf(xp.y);
    float x2 = unpackf(xp.z), x3 = unpackf(xp.w);
    float a0 = x0 > 0.f ? x0 : 0.2f * x0;
    float a1 = x1 > 0.f ? x1 : 0.2f * x1;
    float a2 = x2 > 0.f ? x2 : 0.2f * x2;
    float a3 = x3 > 0.f ? x3 : 0.2f * x3;
    float mean = wred(a0 + a1 + a2 + a3) * (1.f / D);
    float c0 = a0 - mean, c1 = a1 - mean, c2 = a2 - mean, c3 = a3 - mean;
    float var = wred(c0 * c0 + c1 * c1 + c2 * c2 + c3 * c3) * (1.f / D);
    float rstd = rsqrtf(var + 1e-5f);
    int d0 = lane * 4;
    ushort4 o;
    o.x = f2b(c0 * rstd * g[d0 + 0] + bb[d0 + 0]);
    o.y = f2b(c1 * rstd * g[d0 + 1] + bb[d0 + 1]);
    o.z = f2b(c2 * rstd * g[d0 + 2] + bb[d0 + 2]);
    o.w = f2b(c3 * rstd * g[d0 + 3] + bb[d0 + 3]);
    *(ushort4*)(out + base) = o;
}

// ---------------- out[e0+le] = dot(LN(h+q), Wvec) + bvec (u16 h, u16 q) ----------------
__global__ __launch_bounds__(256)
void final_k(const u16* __restrict__ hp, const u16* __restrict__ qp,
             const float* __restrict__ gfin, const float* __restrict__ bfin,
             const float* __restrict__ wvec, const float* __restrict__ bvec,
             float* __restrict__ out, int e0, int cm)
{
    int le = blockIdx.x * 4 + (threadIdx.x >> 6);
    int lane = threadIdx.x & 63;
    if (le >= cm) return;
    size_t base = (size_t)le * D + lane * 4;
    ushort4 hv = *(const ushort4*)(hp + base);
    ushort4 qv = *(const ushort4*)(qp + base);
    float a0 = b2f(hv.x) + b2f(qv.x);
    float a1 = b2f(hv.y) + b2f(qv.y);
    float a2 = b2f(hv.z) + b2f(qv.z);
    float a3 = b2f(hv.w) + b2f(qv.w);
    float mean = wred(a0 + a1 + a2 + a3) * (1.f / D);
    float c0 = a0 - mean, c1 = a1 - mean, c2 = a2 - mean, c3 = a3 - mean;
    float var = wred(c0 * c0 + c1 * c1 + c2 * c2 + c3 * c3) * (1.f / D);
    float rstd = rsqrtf(var + 1e-5f);
    int d0 = lane * 4;
    float t0 = c0 * rstd * gfin[d0 + 0] + bfin[d0 + 0];
    float t1 = c1 * rstd * gfin[d0 + 1] + bfin[d0 + 1];
    float t2 = c2 * rstd * gfin[d0 + 2] + bfin[d0 + 2];
    float t3 = c3 * rstd * gfin[d0 + 3] + bfin[d0 + 3];
    float part = t0 * wvec[d0 + 0] + t1 * wvec[d0 + 1] +
                 t2 * wvec[d0 + 2] + t3 * wvec[d0 + 3];
    part = wred(part);
    if (lane == 0) out[e0 + le] = part + bvec[0];
}

extern "C" void kernel_launch(void* const* d_in, const int* in_sizes, int n_in,
                              void* d_out, int out_size, void* d_ws, size_t ws_size,
                              hipStream_t stream)
{
    const int*   ei   = (const int*)d_in[0];
    const float* x    = (const float*)d_in[1];
    const float* Wq   = (const float*)d_in[2];
    const float* bq   = (const float*)d_in[3];
    const float* Wk   = (const float*)d_in[4];
    const float* bk   = (const float*)d_in[5];
    const float* Wv   = (const float*)d_in[6];
    const float* bv   = (const float*)d_in[7];
    const float* Wff  = (const float*)d_in[8];
    const float* bff  = (const float*)d_in[9];
    const float* ga   = (const float*)d_in[10];
    const float* ba   = (const float*)d_in[11];
    const float* gf   = (const float*)d_in[12];
    const float* bf   = (const float*)d_in[13];
    const float* gfin = (const float*)d_in[14];
    const float* bfin = (const float*)d_in[15];
    const float* W3   = (const float*)d_in[16];
    const float* b3   = (const float*)d_in[17];
    const float* W4   = (const float*)d_in[18];
    const float* b4   = (const float*)d_in[19];
    const float* W5   = (const float*)d_in[20];
    const float* b5   = (const float*)d_in[21];
    const float* Wvec = (const float*)d_in[22];
    const float* bvec = (const float*)d_in[23];

    const int E  = in_sizes[0] / 2;     // 160000 (=1250*128)
    const int Nn = in_sizes[1] / D;
    const int* src = ei;
    const int* dst = ei + E;

    // ---- workspace carve: fixed region ----
    char* base = (char*)d_ws;
    size_t off = 0;
    auto take = [&](size_t bytes) -> void* {
        off = (off + 255) & ~(size_t)255;
        void* r = base + off;
        off += bytes;
        return r;
    };
    float* nK1 = (float*)take((size_t)Nn * D * 4);
    float* nV1 = (float*)take((size_t)Nn * D * 4);
    u16*   q1  = (u16*)take((size_t)E * D * 2);          // hi-only bf16
    float* alpha = (float*)take((size_t)E * 4);
    float* ebuf  = (float*)take((size_t)E * 4);
    u32*   amax  = (u32*)take((size_t)Nn * 4);
    float* denom = (float*)take((size_t)Nn * 4);
    u16* wff0h = (u16*)take((size_t)D * D * 2); u16* wff0l = (u16*)take((size_t)D * D * 2);
    u16* wff1h = (u16*)take((size_t)D * D * 2); u16* wff1l = (u16*)take((size_t)D * D * 2);
    u16* wq1h  = (u16*)take((size_t)D * D * 2); u16* wq1l  = (u16*)take((size_t)D * D * 2);
    u16* w3h = (u16*)take((size_t)3 * D * D * 2);
    u16* w4h = (u16*)take((size_t)9 * D * D * 2);
    u16* w5h = (u16*)take((size_t)3 * D * D * 2);

    // ---- adaptive chunk: area = c1p(CM*1024) + c2p(CM*1024) + zone ----
    const size_t nodeB = (size_t)3 * Nn * D * 4;
    size_t rem = ws_size > off + 8192 ? ws_size - off - 8192 : 0;
    size_t cmA = rem / 4096;
    size_t cmB = rem > nodeB ? (rem - nodeB) / 2048 : 0;
    size_t CMs = (cmA * 2048 >= nodeB) ? cmA : cmB;
    CMs = (CMs / 128) * 128;
    if (CMs > (size_t)E) CMs = E;
    if (CMs < 128) CMs = 128;
    const int CM = (int)CMs;

    u32* c1p = (u32*)take((size_t)CM * D * 4);
    u32* c2p = (u32*)take((size_t)CM * D * 4);
    size_t zoneB = (size_t)CM * 2048 > nodeB ? (size_t)CM * 2048 : nodeB;
    char* zone = (char*)take(zoneB);
    u16* c2n = (u16*)zone;                                // CM*D u16
    u16* c3  = (u16*)(zone + (size_t)CM * D * 2);         // CM*3D u16
    float* nQ0 = (float*)zone;                            // pass-0/1 only
    float* nK0 = nQ0 + (size_t)Nn * D;
    float* nV0 = nK0 + (size_t)Nn * D;
    u16* c4 = (u16*)c1p;                                  // CM*3D u16
    u16* c5 = (u16*)((char*)c1p + (size_t)CM * 3 * D * 2);// CM*D u16

    dim3 blk(256);
    dim3 blk2(512);
    dim3 gNode((Nn + BM - 1) / BM, D / BN);
    int gridSeg = (Nn + 255) / 256;
    int gridE4  = (E + 3) / 4;
    int gridE   = (E + 255) / 256;

    // ---- weight conversion ----
    wconv<<<(D * D + 255) / 256, 256, 0, stream>>>(Wff,          wff0h, wff0l, D * D);
    wconv<<<(D * D + 255) / 256, 256, 0, stream>>>(Wff + D * D,  wff1h, wff1l, D * D);
    wconv<<<(D * D + 255) / 256, 256, 0, stream>>>(Wq + D * D,   wq1h,  wq1l,  D * D);
    wconv<<<(3 * D * D + 255) / 256, 256, 0, stream>>>(W3, w3h, (u16*)nullptr, 3 * D * D);
    wconv<<<(9 * D * D + 255) / 256, 256, 0, stream>>>(W4, w4h, (u16*)nullptr, 9 * D * D);
    wconv<<<(3 * D * D + 255) / 256, 256, 0, stream>>>(W5, w5h, (u16*)nullptr, 3 * D * D);

    // ---- node projections (fp32 vector GEMM) ----
    gemm_awt<<<gNode, blk, 0, stream>>>(x, Wq,         bq,     nQ0, Nn, D, D);
    gemm_awt<<<gNode, blk, 0, stream>>>(x, Wk,         bk,     nK0, Nn, D, D);
    gemm_awt<<<gNode, blk, 0, stream>>>(x, Wv,         bv,     nV0, Nn, D, D);
    gemm_awt<<<gNode, blk, 0, stream>>>(x, Wk + D * D, bk + D, nK1, Nn, D, D);
    gemm_awt<<<gNode, blk, 0, stream>>>(x, Wv + D * D, bv + D, nV1, Nn, D, D);

    // ---- layer-0 segment softmax (fp32 exact) ----
    seg_init<<<gridSeg, 256, 0, stream>>>(amax, denom, Nn);
    attn_alpha<float, 0><<<gridE4, blk, 0, stream>>>(src, dst, nQ0, nK0, alpha, amax, E);
    seg_exp<<<gridE, 256, 0, stream>>>(dst, alpha, amax, ebuf, denom, E);

    // ---- pass 1 (chunked): attnLN0 -> Wff0 -> Wq1 -> q1 (bf16 hi) ----
    for (int e0 = 0; e0 < E; e0 += CM) {
        int cm = E - e0 < CM ? E - e0 : CM;
        int gE4 = (cm + 3) / 4;
        dim3 gD3(cm / 128);
        attn_out_ln<float, 0><<<gE4, blk, 0, stream>>>(src, dst, nQ0, nV0, ebuf, denom,
                                                       ga, ba, c1p, e0, cm);
        gemm3w<<<gD3, blk2, 0, stream>>>(c1p, wff0h, wff0l, bff,
                                         c2p, (u16*)nullptr, cm, D, 0);
        gemm3w<<<gD3, blk2, 0, stream>>>(c2p, wq1h, wq1l, bq + D,
                                         (u32*)nullptr, q1 + (size_t)e0 * D,
                                         cm, D, 0);
    }

    // ---- layer-1 segment softmax ----
    seg_init<<<gridSeg, 256, 0, stream>>>(amax, denom, Nn);
    attn_alpha<u16, 1><<<gridE4, blk, 0, stream>>>(src, dst, q1, nK1, alpha, amax, E);
    seg_exp<<<gridE, 256, 0, stream>>>(dst, alpha, amax, ebuf, denom, E);

    // ---- pass 2 (chunked) ----
    for (int e0 = 0; e0 < E; e0 += CM) {
        int cm = E - e0 < CM ? E - e0 : CM;
        int gE4 = (cm + 3) / 4;
        dim3 gD3(cm / 128);
        dim3 g2a(cm / 128, (3 * D) / 256);   // 128x256 tiles, 3 col sweeps
        dim3 g2b(cm / 128, D / 256);         // 1 col sweep
        attn_out_ln<u16, 1><<<gE4, blk, 0, stream>>>(src, dst, q1, nV1, ebuf, denom,
                                                     ga + D, ba + D, c1p, e0, cm);
        gemm3w<<<gD3, blk2, 0, stream>>>(c1p, wff1h, wff1l, bff + D,
                                         c2p, (u16*)nullptr, cm, D, 0);
        lrelu_ln<<<gE4, blk, 0, stream>>>(c2p, gf, bf, c2n, cm);
        gemm2<1><<<g2a, blk2, 0, stream>>>(c2n, w3h, b3, c3, cm, 3 * D, D);
        gemm2<1><<<g2a, blk2, 0, stream>>>(c3, w4h, b4, c4, cm, 3 * D, 3 * D);
        gemm2<0><<<g2b, blk2, 0, stream>>>(c4, w5h, b5, c5, cm, D, 3 * D);
        final_k<<<gE4, blk, 0, stream>>>(c5, c2n, gfin, bfin, Wvec, bvec,
                                         (float*)d_out, e0, cm);
    }
}

// Round 13
// 1476.334 us; speedup vs baseline: 1.1493x; 1.0729x over previous
//
#include <hip/hip_runtime.h>

#define D 256

typedef unsigned short u16;
typedef unsigned int u32;
typedef __attribute__((ext_vector_type(8))) short short8;
typedef __attribute__((ext_vector_type(4))) float f32x4;
typedef __attribute__((ext_vector_type(16))) float f32x16;

// ---------------- bf16 <-> f32, split-pack ----------------
__device__ __forceinline__ float b2f(u16 u) {
    return __uint_as_float(((u32)u) << 16);
}
__device__ __forceinline__ u16 f2b(float f) {
    u32 u = __float_as_uint(f);
    return (u16)((u + 0x7FFFu + ((u >> 16) & 1u)) >> 16);  // RNE
}
__device__ __forceinline__ u32 packf(float v) {
    u16 h = f2b(v);
    u16 l = f2b(v - b2f(h));
    return ((u32)h << 16) | l;
}
__device__ __forceinline__ float unpackf(u32 p) {
    return b2f((u16)(p >> 16)) + b2f((u16)(p & 0xffffu));
}
template<typename T> __device__ __forceinline__ float ld1(const T* p);
template<> __device__ __forceinline__ float ld1<u16>(const u16* p) { return b2f(*p); }
template<> __device__ __forceinline__ float ld1<u32>(const u32* p) { return unpackf(*p); }

// ---------------- ordered-uint float atomic max ----------------
__device__ __forceinline__ u32 f2ord(float f) {
    u32 b = __float_as_uint(f);
    return (b & 0x80000000u) ? ~b : (b | 0x80000000u);
}
__device__ __forceinline__ float ord2f(u32 u) {
    return (u & 0x80000000u) ? __uint_as_float(u & 0x7fffffffu)
                             : __uint_as_float(~u);
}

__device__ __forceinline__ float wred(float v) {
#pragma unroll
    for (int m = 32; m; m >>= 1) v += __shfl_xor(v, m);
    return v;
}

// async global(16B/lane) -> LDS (wave-uniform base + lane*16)
__device__ __forceinline__ void gl_lds16(const u16* g, u16* l) {
    __builtin_amdgcn_global_load_lds(
        (__attribute__((address_space(1))) void*)(u16*)g,
        (__attribute__((address_space(3))) void*)l, 16, 0, 0);
}

// ======== gemm2: single-term (hi-only W) MFMA GEMM (head MLP), BK=64 ========
// C = act(A[M,K] @ W[N,K]^T + b). A bf16 u16; W hi-plane u16.
// 512 threads: block tile 128x256, wave grid 2x4, wave tile 64x64.
// 32x32x16 MFMA, BK=64 (12 K-steps at K=768). M%128==0, N%256==0, K%64==0.
// 8-slot XOR swizzle: slot s of row r holds global k-chunk s^(r&7).
template<int ACT>
__global__ __launch_bounds__(512, 4)
void gemm2(const u16* __restrict__ A, const u16* __restrict__ Whi,
           const float* __restrict__ bias, u16* __restrict__ C,
           int M, int N, int K)
{
    __shared__ u16 sA[128 * 64];       // 16 KB
    __shared__ u16 sWh[256 * 64];      // 32 KB

    const int tid  = threadIdx.x;
    const int lane = tid & 63;
    const int w    = tid >> 6;             // wave 0..7
    const int wm   = (w & 1) * 64;
    const int wn   = (w >> 1) * 64;
    const int row0 = blockIdx.x * 128;
    const int col0 = blockIdx.y * 256;

    f32x16 acc[2][2];
#pragma unroll
    for (int i = 0; i < 2; ++i)
#pragma unroll
        for (int j = 0; j < 2; ++j)
#pragma unroll
            for (int r = 0; r < 16; ++r) acc[i][j][r] = 0.f;

    const int r31   = lane & 31;
    const int khalf = lane >> 5;
    const int skey  = r31 & 7;
    const int l8r = lane >> 3;             // DMA: row-in-seg 0..7
    const int l8c = lane & 7;              // DMA: slot 0..7

    for (int k0 = 0; k0 < K; k0 += 64) {
        // stage W hi-plane: 256 rows x 64k; 8 waves x 4 segs x 8 rows
#pragma unroll
        for (int s = 0; s < 4; ++s) {
            const int rbase = w * 32 + s * 8;           // wave-uniform
            const int row = rbase + l8r;
            const int gch = l8c ^ (row & 7);
            const size_t gW = (size_t)(col0 + row) * K + k0 + gch * 8;
            gl_lds16(Whi + gW, sWh + rbase * 64);
        }
        // stage A via VGPR: 128x64 u16 = 16 KB, 2 x uint4 per thread
#pragma unroll
        for (int it = 0; it < 2; ++it) {
            const int u = tid + it * 512;
            const int ar = u >> 3;
            const int ch = u & 7;
            uint4 pk = *(const uint4*)(A + (size_t)(row0 + ar) * K + k0 + ch * 8);
            const int slot = ch ^ (ar & 7);
            *(uint4*)(sA + ar * 64 + slot * 8) = pk;
        }
        __syncthreads();

#pragma unroll
        for (int w4 = 0; w4 < 4; ++w4) {
            const int slot = ((w4 * 2 + khalf) ^ skey) * 8;
            short8 af[2], wf[2];
#pragma unroll
            for (int i = 0; i < 2; ++i)
                af[i] = *(const short8*)(sA + (wm + i * 32 + r31) * 64 + slot);
#pragma unroll
            for (int j = 0; j < 2; ++j)
                wf[j] = *(const short8*)(sWh + (wn + j * 32 + r31) * 64 + slot);
#pragma unroll
            for (int i = 0; i < 2; ++i)
#pragma unroll
                for (int j = 0; j < 2; ++j)
                    acc[i][j] = __builtin_amdgcn_mfma_f32_32x32x16_bf16(af[i], wf[j], acc[i][j], 0, 0, 0);
        }
        __syncthreads();
    }

    // epilogue: scalar stores. C/D: col=lane&31, row=(reg&3)+8*(reg>>2)+4*khalf
#pragma unroll
    for (int j = 0; j < 2; ++j) {
        const int col = col0 + wn + j * 32 + r31;
        const float bb = bias[col];
#pragma unroll
        for (int i = 0; i < 2; ++i) {
            const int rowb = row0 + wm + i * 32 + 4 * khalf;
#pragma unroll
            for (int reg = 0; reg < 16; ++reg) {
                const int row = rowb + (reg & 3) + 8 * (reg >> 2);
                float v = acc[i][j][reg] + bb;
                if (ACT) v = v > 0.f ? v : 0.2f * v;
                C[(size_t)row * N + col] = f2b(v);
            }
        }
    }
}

// ======== gemm3w: 3-term split MFMA GEMM, N=256 single-sweep (chunks) ========
// A packed u32 (hi<<16|lo). W hi/lo planes. 16x16x32, BK=32. M%128==0.
__global__ __launch_bounds__(512, 4)
void gemm3w(const u32* __restrict__ Ap,
            const u16* __restrict__ Whi, const u16* __restrict__ Wlo,
            const float* __restrict__ bias,
            u32* __restrict__ Cp, u16* __restrict__ Chi,
            int M, int K, int act)
{
    constexpr int N = 256;
    __shared__ u16 sAhi[128 * 32];
    __shared__ u16 sAlo[128 * 32];
    __shared__ u16 sWhi[256 * 32];
    __shared__ u16 sWlo[256 * 32];

    const int tid  = threadIdx.x;
    const int lane = tid & 63;
    const int w    = tid >> 6;
    const int wm   = (w & 1) * 64;
    const int wn   = (w >> 1) * 64;
    const int row0 = blockIdx.x * 128;

    f32x4 acc[4][4];
#pragma unroll
    for (int i = 0; i < 4; ++i)
#pragma unroll
        for (int j = 0; j < 4; ++j) acc[i][j] = (f32x4){0.f, 0.f, 0.f, 0.f};

    const int lrow = lane >> 2;
    const int gck  = (lane & 3) ^ ((lane >> 3) & 3);
    const int r15 = lane & 15;
    const int rck = ((lane >> 4) ^ ((r15 >> 1) & 3)) * 8;

    for (int k0 = 0; k0 < K; k0 += 32) {
#pragma unroll
        for (int s = 0; s < 2; ++s) {
            const int rbase = w * 32 + s * 16;
            const size_t gW = (size_t)(rbase + lrow) * K + k0 + gck * 8;
            gl_lds16(Whi + gW, sWhi + rbase * 32);
            gl_lds16(Wlo + gW, sWlo + rbase * 32);
        }
#pragma unroll
        for (int it = 0; it < 2; ++it) {
            const int u = tid + it * 512;
            const int ar = u >> 3;
            const int pos = u & 7;
            uint4 pk = *(const uint4*)(Ap + (size_t)(row0 + ar) * K + k0 + pos * 4);
            const int slot = (pos >> 1) ^ ((ar >> 1) & 3);
            const int base = ar * 32 + slot * 8 + (pos & 1) * 4;
            ushort4 h4, l4;
            h4.x = (u16)(pk.x >> 16); l4.x = (u16)(pk.x & 0xffffu);
            h4.y = (u16)(pk.y >> 16); l4.y = (u16)(pk.y & 0xffffu);
            h4.z = (u16)(pk.z >> 16); l4.z = (u16)(pk.z & 0xffffu);
            h4.w = (u16)(pk.w >> 16); l4.w = (u16)(pk.w & 0xffffu);
            *(ushort4*)(sAhi + base) = h4;
            *(ushort4*)(sAlo + base) = l4;
        }
        __syncthreads();

        short8 ah[4], al[4], wh[4], wl[4];
#pragma unroll
        for (int i = 0; i < 4; ++i) {
            const int offA = (wm + i * 16 + r15) * 32 + rck;
            ah[i] = *(const short8*)(sAhi + offA);
            al[i] = *(const short8*)(sAlo + offA);
        }
#pragma unroll
        for (int j = 0; j < 4; ++j) {
            const int offW = (wn + j * 16 + r15) * 32 + rck;
            wh[j] = *(const short8*)(sWhi + offW);
            wl[j] = *(const short8*)(sWlo + offW);
        }
#pragma unroll
        for (int i = 0; i < 4; ++i)
#pragma unroll
            for (int j = 0; j < 4; ++j) {
                acc[i][j] = __builtin_amdgcn_mfma_f32_16x16x32_bf16(ah[i], wh[j], acc[i][j], 0, 0, 0);
                acc[i][j] = __builtin_amdgcn_mfma_f32_16x16x32_bf16(ah[i], wl[j], acc[i][j], 0, 0, 0);
                acc[i][j] = __builtin_amdgcn_mfma_f32_16x16x32_bf16(al[i], wh[j], acc[i][j], 0, 0, 0);
            }
        __syncthreads();
    }

#pragma unroll
    for (int j = 0; j < 4; ++j) {
        const int col = wn + j * 16 + r15;
        const float bb = bias[col];
#pragma unroll
        for (int i = 0; i < 4; ++i) {
            const int rowb = row0 + wm + i * 16 + (lane >> 4) * 4;
#pragma unroll
            for (int r = 0; r < 4; ++r) {
                float v = acc[i][j][r] + bb;
                if (act) v = v > 0.f ? v : 0.2f * v;
                const size_t idx = (size_t)(rowb + r) * N + col;
                if (Cp) Cp[idx] = packf(v);
                else    Chi[idx] = f2b(v);
            }
        }
    }
}

// ======== gemm3n: node-projection batched GEMM (M-guarded, grid.y=weight) ========
// Same math as gemm3w (3-term exact split). W stacked [NY][256][K]; C stacked
// [NY][M][256] packed u32. bias selected from b0/b1/b2 by blockIdx.y.
__global__ __launch_bounds__(512, 4)
void gemm3n(const u32* __restrict__ Ap,
            const u16* __restrict__ Whi, const u16* __restrict__ Wlo,
            const float* __restrict__ b0, const float* __restrict__ b1,
            const float* __restrict__ b2,
            u32* __restrict__ Cp, int M, int K)
{
    constexpr int N = 256;
    __shared__ u16 sAhi[128 * 32];
    __shared__ u16 sAlo[128 * 32];
    __shared__ u16 sWhi[256 * 32];
    __shared__ u16 sWlo[256 * 32];

    const int tid  = threadIdx.x;
    const int lane = tid & 63;
    const int w    = tid >> 6;
    const int wm   = (w & 1) * 64;
    const int wn   = (w >> 1) * 64;
    const int row0 = blockIdx.x * 128;
    const int y    = blockIdx.y;
    const float* bias = (y == 0) ? b0 : ((y == 1) ? b1 : b2);
    const u16* Wh = Whi + (size_t)y * N * K;
    const u16* Wl = Wlo + (size_t)y * N * K;
    u32* Cy = Cp + (size_t)y * M * N;

    f32x4 acc[4][4];
#pragma unroll
    for (int i = 0; i < 4; ++i)
#pragma unroll
        for (int j = 0; j < 4; ++j) acc[i][j] = (f32x4){0.f, 0.f, 0.f, 0.f};

    const int lrow = lane >> 2;
    const int gck  = (lane & 3) ^ ((lane >> 3) & 3);
    const int r15 = lane & 15;
    const int rck = ((lane >> 4) ^ ((r15 >> 1) & 3)) * 8;

    for (int k0 = 0; k0 < K; k0 += 32) {
#pragma unroll
        for (int s = 0; s < 2; ++s) {
            const int rbase = w * 32 + s * 16;
            const size_t gW = (size_t)(rbase + lrow) * K + k0 + gck * 8;
            gl_lds16(Wh + gW, sWhi + rbase * 32);
            gl_lds16(Wl + gW, sWlo + rbase * 32);
        }
#pragma unroll
        for (int it = 0; it < 2; ++it) {
            const int u = tid + it * 512;
            const int ar = u >> 3;
            const int pos = u & 7;
            int arc = row0 + ar; if (arc >= M) arc = M - 1;   // row guard
            uint4 pk = *(const uint4*)(Ap + (size_t)arc * K + k0 + pos * 4);
            const int slot = (pos >> 1) ^ ((ar >> 1) & 3);
            const int base = ar * 32 + slot * 8 + (pos & 1) * 4;
            ushort4 h4, l4;
            h4.x = (u16)(pk.x >> 16); l4.x = (u16)(pk.x & 0xffffu);
            h4.y = (u16)(pk.y >> 16); l4.y = (u16)(pk.y & 0xffffu);
            h4.z = (u16)(pk.z >> 16); l4.z = (u16)(pk.z & 0xffffu);
            h4.w = (u16)(pk.w >> 16); l4.w = (u16)(pk.w & 0xffffu);
            *(ushort4*)(sAhi + base) = h4;
            *(ushort4*)(sAlo + base) = l4;
        }
        __syncthreads();

        short8 ah[4], al[4], wh[4], wl[4];
#pragma unroll
        for (int i = 0; i < 4; ++i) {
            const int offA = (wm + i * 16 + r15) * 32 + rck;
            ah[i] = *(const short8*)(sAhi + offA);
            al[i] = *(const short8*)(sAlo + offA);
        }
#pragma unroll
        for (int j = 0; j < 4; ++j) {
            const int offW = (wn + j * 16 + r15) * 32 + rck;
            wh[j] = *(const short8*)(sWhi + offW);
            wl[j] = *(const short8*)(sWlo + offW);
        }
#pragma unroll
        for (int i = 0; i < 4; ++i)
#pragma unroll
            for (int j = 0; j < 4; ++j) {
                acc[i][j] = __builtin_amdgcn_mfma_f32_16x16x32_bf16(ah[i], wh[j], acc[i][j], 0, 0, 0);
                acc[i][j] = __builtin_amdgcn_mfma_f32_16x16x32_bf16(ah[i], wl[j], acc[i][j], 0, 0, 0);
                acc[i][j] = __builtin_amdgcn_mfma_f32_16x16x32_bf16(al[i], wh[j], acc[i][j], 0, 0, 0);
            }
        __syncthreads();
    }

#pragma unroll
    for (int j = 0; j < 4; ++j) {
        const int col = wn + j * 16 + r15;
        const float bb = bias[col];
#pragma unroll
        for (int i = 0; i < 4; ++i) {
            const int rowb = row0 + wm + i * 16 + (lane >> 4) * 4;
#pragma unroll
            for (int r = 0; r < 4; ++r) {
                const int row = rowb + r;
                if (row < M)
                    Cy[(size_t)row * N + col] = packf(acc[i][j][r] + bb);
            }
        }
    }
}

// ---------------- x fp32 -> packed u32 ----------------
__global__ void pack_x(const float* __restrict__ x, u32* __restrict__ xp, int n)
{
    int i = blockIdx.x * 256 + threadIdx.x;
    if (i < n) xp[i] = packf(x[i]);
}

// ---------------- weight fp32 -> hi (and optional lo) bf16 planes ----------------
__global__ void wconv(const float* __restrict__ wsrc, u16* __restrict__ hi,
                      u16* __restrict__ lo, int n)
{
    int i = blockIdx.x * 256 + threadIdx.x;
    if (i < n) {
        float v = wsrc[i];
        u16 h = f2b(v);
        hi[i] = h;
        if (lo) lo[i] = f2b(v - b2f(h));
    }
}

// ---------------- segment-softmax ----------------
__global__ void seg_init(u32* __restrict__ amax, float* __restrict__ denom, int n)
{
    int i = blockIdx.x * 256 + threadIdx.x;
    if (i < n) { amax[i] = 0u; denom[i] = 0.f; }
}

template<typename TQ, int MODE>
__global__ __launch_bounds__(256)
void attn_alpha(const int* __restrict__ src, const int* __restrict__ dst,
                const TQ* __restrict__ qn, const u32* __restrict__ kn,
                float* __restrict__ alpha, u32* __restrict__ amax, int E)
{
    int e = blockIdx.x * 4 + (threadIdx.x >> 6);
    int lane = threadIdx.x & 63;
    if (e >= E) return;
    int s = src[e], d = dst[e];
    const TQ* qp = MODE ? (qn + (size_t)e * D) : (qn + (size_t)d * D);
    const u32* kp = kn + (size_t)s * D;
    float dot = 0.f;
#pragma unroll
    for (int j = 0; j < 4; ++j)
        dot += ld1(qp + lane * 4 + j) * unpackf(kp[lane * 4 + j]);
    dot = wred(dot);
    if (lane == 0) {
        alpha[e] = dot;
        atomicMax(amax + d, f2ord(dot));
    }
}

__global__ void seg_exp(const int* __restrict__ dst, const float* __restrict__ alpha,
                        const u32* __restrict__ amax, float* __restrict__ ebuf,
                        float* __restrict__ denom, int E)
{
    int e = blockIdx.x * 256 + threadIdx.x;
    if (e >= E) return;
    int d = dst[e];
    float ex = expf(alpha[e] - ord2f(amax[d]));
    ebuf[e] = ex;
    atomicAdd(denom + d, ex);
}

// ---------------- out(local, packed) = LN(q + attn*v[src]) ----------------
template<typename TQ, int MODE>
__global__ __launch_bounds__(256)
void attn_out_ln(const int* __restrict__ src, const int* __restrict__ dst,
                 const TQ* __restrict__ qn, const u32* __restrict__ vn,
                 const float* __restrict__ ebuf, const float* __restrict__ denom,
                 const float* __restrict__ g, const float* __restrict__ bb,
                 u32* __restrict__ outp, int e0, int cm)
{
    int le = blockIdx.x * 4 + (threadIdx.x >> 6);
    int lane = threadIdx.x & 63;
    if (le >= cm) return;
    int ge = e0 + le;
    int s = src[ge], d = dst[ge];
    float attn = ebuf[ge] / denom[d];
    const TQ* qp = MODE ? (qn + (size_t)ge * D) : (qn + (size_t)d * D);
    const u32* vp = vn + (size_t)s * D;
    int d0 = lane * 4;
    float a0 = ld1(qp + d0 + 0) + attn * unpackf(vp[d0 + 0]);
    float a1 = ld1(qp + d0 + 1) + attn * unpackf(vp[d0 + 1]);
    float a2 = ld1(qp + d0 + 2) + attn * unpackf(vp[d0 + 2]);
    float a3 = ld1(qp + d0 + 3) + attn * unpackf(vp[d0 + 3]);
    float mean = wred(a0 + a1 + a2 + a3) * (1.f / D);
    float c0 = a0 - mean, c1 = a1 - mean, c2 = a2 - mean, c3 = a3 - mean;
    float var = wred(c0 * c0 + c1 * c1 + c2 * c2 + c3 * c3) * (1.f / D);
    float rstd = rsqrtf(var + 1e-5f);
    uint4 p;
    p.x = packf(c0 * rstd * g[d0 + 0] + bb[d0 + 0]);
    p.y = packf(c1 * rstd * g[d0 + 1] + bb[d0 + 1]);
    p.z = packf(c2 * rstd * g[d0 + 2] + bb[d0 + 2]);
    p.w = packf(c3 * rstd * g[d0 + 3] + bb[d0 + 3]);
    *(uint4*)(outp + (size_t)le * D + d0) = p;
}

// ---------------- y = LN(lrelu(x)), packed u32 -> bf16 u16 ----------------
__global__ __launch_bounds__(256)
void lrelu_ln(const u32* __restrict__ inp, const float* __restrict__ g,
              const float* __restrict__ bb, u16* __restrict__ out, int cm)
{
    int le = blockIdx.x * 4 + (threadIdx.x >> 6);
    int lane = threadIdx.x & 63;
    if (le >= cm) return;
    size_t base = (size_t)le * D + lane * 4;
    uint4 xp = *(const uint4*)(inp + base);
    float x0 = unpackf(xp.x), x1 = unpackf(xp.y);
    float x2 = unpackf(xp.z), x3 = unpackf(xp.w);
    float a0 = x0 > 0.f ? x0 : 0.2f * x0;
    float a1 = x1 > 0.f ? x1 : 0.2f * x1;
    float a2 = x2 > 0.f ? x2 : 0.2f * x2;
    float a3 = x3 > 0.f ? x3 : 0.2f * x3;
    float mean = wred(a0 + a1 + a2 + a3) * (1.f / D);
    float c0 = a0 - mean, c1 = a1 - mean, c2 = a2 - mean, c3 = a3 - mean;
    float var = wred(c0 * c0 + c1 * c1 + c2 * c2 + c3 * c3) * (1.f / D);
    float rstd = rsqrtf(var + 1e-5f);
    int d0 = lane * 4;
    ushort4 o;
    o.x = f2b(c0 * rstd * g[d0 + 0] + bb[d0 + 0]);
    o.y = f2b(c1 * rstd * g[d0 + 1] + bb[d0 + 1]);
    o.z = f2b(c2 * rstd * g[d0 + 2] + bb[d0 + 2]);
    o.w = f2b(c3 * rstd * g[d0 + 3] + bb[d0 + 3]);
    *(ushort4*)(out + base) = o;
}

// ---------------- out[e0+le] = dot(LN(h+q), Wvec) + bvec (u16 h, u16 q) ----------------
__global__ __launch_bounds__(256)
void final_k(const u16* __restrict__ hp, const u16* __restrict__ qp,
             const float* __restrict__ gfin, const float* __restrict__ bfin,
             const float* __restrict__ wvec, const float* __restrict__ bvec,
             float* __restrict__ out, int e0, int cm)
{
    int le = blockIdx.x * 4 + (threadIdx.x >> 6);
    int lane = threadIdx.x & 63;
    if (le >= cm) return;
    size_t base = (size_t)le * D + lane * 4;
    ushort4 hv = *(const ushort4*)(hp + base);
    ushort4 qv = *(const ushort4*)(qp + base);
    float a0 = b2f(hv.x) + b2f(qv.x);
    float a1 = b2f(hv.y) + b2f(qv.y);
    float a2 = b2f(hv.z) + b2f(qv.z);
    float a3 = b2f(hv.w) + b2f(qv.w);
    float mean = wred(a0 + a1 + a2 + a3) * (1.f / D);
    float c0 = a0 - mean, c1 = a1 - mean, c2 = a2 - mean, c3 = a3 - mean;
    float var = wred(c0 * c0 + c1 * c1 + c2 * c2 + c3 * c3) * (1.f / D);
    float rstd = rsqrtf(var + 1e-5f);
    int d0 = lane * 4;
    float t0 = c0 * rstd * gfin[d0 + 0] + bfin[d0 + 0];
    float t1 = c1 * rstd * gfin[d0 + 1] + bfin[d0 + 1];
    float t2 = c2 * rstd * gfin[d0 + 2] + bfin[d0 + 2];
    float t3 = c3 * rstd * gfin[d0 + 3] + bfin[d0 + 3];
    float part = t0 * wvec[d0 + 0] + t1 * wvec[d0 + 1] +
                 t2 * wvec[d0 + 2] + t3 * wvec[d0 + 3];
    part = wred(part);
    if (lane == 0) out[e0 + le] = part + bvec[0];
}

extern "C" void kernel_launch(void* const* d_in, const int* in_sizes, int n_in,
                              void* d_out, int out_size, void* d_ws, size_t ws_size,
                              hipStream_t stream)
{
    const int*   ei   = (const int*)d_in[0];
    const float* x    = (const float*)d_in[1];
    const float* Wq   = (const float*)d_in[2];
    const float* bq   = (const float*)d_in[3];
    const float* Wk   = (const float*)d_in[4];
    const float* bk   = (const float*)d_in[5];
    const float* Wv   = (const float*)d_in[6];
    const float* bv   = (const float*)d_in[7];
    const float* Wff  = (const float*)d_in[8];
    const float* bff  = (const float*)d_in[9];
    const float* ga   = (const float*)d_in[10];
    const float* ba   = (const float*)d_in[11];
    const float* gf   = (const float*)d_in[12];
    const float* bf   = (const float*)d_in[13];
    const float* gfin = (const float*)d_in[14];
    const float* bfin = (const float*)d_in[15];
    const float* W3   = (const float*)d_in[16];
    const float* b3   = (const float*)d_in[17];
    const float* W4   = (const float*)d_in[18];
    const float* b4   = (const float*)d_in[19];
    const float* W5   = (const float*)d_in[20];
    const float* b5   = (const float*)d_in[21];
    const float* Wvec = (const float*)d_in[22];
    const float* bvec = (const float*)d_in[23];

    const int E  = in_sizes[0] / 2;     // 160000 (=1250*128)
    const int Nn = in_sizes[1] / D;
    const int* src = ei;
    const int* dst = ei + E;

    // ---- workspace carve: fixed region ----
    char* base = (char*)d_ws;
    size_t off = 0;
    auto take = [&](size_t bytes) -> void* {
        off = (off + 255) & ~(size_t)255;
        void* r = base + off;
        off += bytes;
        return r;
    };
    u32*   nKV1 = (u32*)take((size_t)2 * Nn * D * 4);    // packed K1,V1
    u16*   q1  = (u16*)take((size_t)E * D * 2);          // hi-only bf16
    float* alpha = (float*)take((size_t)E * 4);
    float* ebuf  = (float*)take((size_t)E * 4);
    u32*   amax  = (u32*)take((size_t)Nn * 4);
    float* denom = (float*)take((size_t)Nn * 4);
    u16* wnh = (u16*)take((size_t)5 * D * D * 2);        // node weights hi (stacked)
    u16* wnl = (u16*)take((size_t)5 * D * D * 2);        // node weights lo
    u16* wff0h = (u16*)take((size_t)D * D * 2); u16* wff0l = (u16*)take((size_t)D * D * 2);
    u16* wff1h = (u16*)take((size_t)D * D * 2); u16* wff1l = (u16*)take((size_t)D * D * 2);
    u16* wq1h  = (u16*)take((size_t)D * D * 2); u16* wq1l  = (u16*)take((size_t)D * D * 2);
    u16* w3h = (u16*)take((size_t)3 * D * D * 2);
    u16* w4h = (u16*)take((size_t)9 * D * D * 2);
    u16* w5h = (u16*)take((size_t)3 * D * D * 2);

    // ---- adaptive chunk: area = c1p(CM*1024) + c2p(CM*1024) + zone ----
    // zone floor = xp + packed Q0,K0,V0 (4 x Nn*D u32), alive only pre-pass-2
    const size_t nodeB = (size_t)4 * Nn * D * 4;
    size_t rem = ws_size > off + 8192 ? ws_size - off - 8192 : 0;
    size_t cmA = rem / 4096;
    size_t cmB = rem > nodeB ? (rem - nodeB) / 2048 : 0;
    size_t CMs = (cmA * 2048 >= nodeB) ? cmA : cmB;
    CMs = (CMs / 128) * 128;
    if (CMs > (size_t)E) CMs = E;
    if (CMs < 128) CMs = 128;
    const int CM = (int)CMs;

    u32* c1p = (u32*)take((size_t)CM * D * 4);
    u32* c2p = (u32*)take((size_t)CM * D * 4);
    size_t zoneB = (size_t)CM * 2048 > nodeB ? (size_t)CM * 2048 : nodeB;
    char* zone = (char*)take(zoneB);
    u16* c2n = (u16*)zone;                                // CM*D u16 (pass 2)
    u16* c3  = (u16*)(zone + (size_t)CM * D * 2);         // CM*3D u16 (pass 2)
    u32* xp   = (u32*)zone;                               // Nn*D packed (pre)
    u32* zQKV = xp + (size_t)Nn * D;                      // packed Q0,K0,V0
    u32* zQ0 = zQKV;
    u32* zK0 = zQKV + (size_t)Nn * D;
    u32* zV0 = zQKV + (size_t)2 * Nn * D;
    u32* nK1 = nKV1;
    u32* nV1 = nKV1 + (size_t)Nn * D;
    u16* c4 = (u16*)c1p;                                  // CM*3D u16
    u16* c5 = (u16*)((char*)c1p + (size_t)CM * 3 * D * 2);// CM*D u16

    dim3 blk(256);
    dim3 blk2(512);
    int gridSeg = (Nn + 255) / 256;
    int gridE4  = (E + 3) / 4;
    int gridE   = (E + 255) / 256;
    const int DD = D * D;

    // ---- pack x, weight conversion ----
    pack_x<<<(Nn * D + 255) / 256, 256, 0, stream>>>(x, xp, Nn * D);
    wconv<<<(DD + 255) / 256, 256, 0, stream>>>(Wq,          wnh + 0 * DD, wnl + 0 * DD, DD);
    wconv<<<(DD + 255) / 256, 256, 0, stream>>>(Wk,          wnh + 1 * DD, wnl + 1 * DD, DD);
    wconv<<<(DD + 255) / 256, 256, 0, stream>>>(Wv,          wnh + 2 * DD, wnl + 2 * DD, DD);
    wconv<<<(DD + 255) / 256, 256, 0, stream>>>(Wk + DD,     wnh + 3 * DD, wnl + 3 * DD, DD);
    wconv<<<(DD + 255) / 256, 256, 0, stream>>>(Wv + DD,     wnh + 4 * DD, wnl + 4 * DD, DD);
    wconv<<<(DD + 255) / 256, 256, 0, stream>>>(Wff,         wff0h, wff0l, DD);
    wconv<<<(DD + 255) / 256, 256, 0, stream>>>(Wff + DD,    wff1h, wff1l, DD);
    wconv<<<(DD + 255) / 256, 256, 0, stream>>>(Wq + DD,     wq1h,  wq1l,  DD);
    wconv<<<(3 * DD + 255) / 256, 256, 0, stream>>>(W3, w3h, (u16*)nullptr, 3 * DD);
    wconv<<<(9 * DD + 255) / 256, 256, 0, stream>>>(W4, w4h, (u16*)nullptr, 9 * DD);
    wconv<<<(3 * DD + 255) / 256, 256, 0, stream>>>(W5, w5h, (u16*)nullptr, 3 * DD);

    // ---- node projections (batched split-bf16 MFMA) ----
    int gN = (Nn + 127) / 128;
    gemm3n<<<dim3(gN, 3), blk2, 0, stream>>>(xp, wnh, wnl, bq, bk, bv,
                                             zQKV, Nn, D);
    gemm3n<<<dim3(gN, 2), blk2, 0, stream>>>(xp, wnh + 3 * DD, wnl + 3 * DD,
                                             bk + D, bv + D, bv,
                                             nKV1, Nn, D);

    // ---- layer-0 segment softmax ----
    seg_init<<<gridSeg, 256, 0, stream>>>(amax, denom, Nn);
    attn_alpha<u32, 0><<<gridE4, blk, 0, stream>>>(src, dst, zQ0, zK0, alpha, amax, E);
    seg_exp<<<gridE, 256, 0, stream>>>(dst, alpha, amax, ebuf, denom, E);

    // ---- pass 1 (chunked): attnLN0 -> Wff0 -> Wq1 -> q1 (bf16 hi) ----
    for (int e0 = 0; e0 < E; e0 += CM) {
        int cm = E - e0 < CM ? E - e0 : CM;
        int gE4 = (cm + 3) / 4;
        dim3 gD3(cm / 128);
        attn_out_ln<u32, 0><<<gE4, blk, 0, stream>>>(src, dst, zQ0, zV0, ebuf, denom,
                                                     ga, ba, c1p, e0, cm);
        gemm3w<<<gD3, blk2, 0, stream>>>(c1p, wff0h, wff0l, bff,
                                         c2p, (u16*)nullptr, cm, D, 0);
        gemm3w<<<gD3, blk2, 0, stream>>>(c2p, wq1h, wq1l, bq + D,
                                         (u32*)nullptr, q1 + (size_t)e0 * D,
                                         cm, D, 0);
    }

    // ---- layer-1 segment softmax ----
    seg_init<<<gridSeg, 256, 0, stream>>>(amax, denom, Nn);
    attn_alpha<u16, 1><<<gridE4, blk, 0, stream>>>(src, dst, q1, nK1, alpha, amax, E);
    seg_exp<<<gridE, 256, 0, stream>>>(dst, alpha, amax, ebuf, denom, E);

    // ---- pass 2 (chunked) ----
    for (int e0 = 0; e0 < E; e0 += CM) {
        int cm = E - e0 < CM ? E - e0 : CM;
        int gE4 = (cm + 3) / 4;
        dim3 gD3(cm / 128);
        dim3 g2a(cm / 128, (3 * D) / 256);
        dim3 g2b(cm / 128, D / 256);
        attn_out_ln<u16, 1><<<gE4, blk, 0, stream>>>(src, dst, q1, nV1, ebuf, denom,
                                                     ga + D, ba + D, c1p, e0, cm);
        gemm3w<<<gD3, blk2, 0, stream>>>(c1p, wff1h, wff1l, bff + D,
                                         c2p, (u16*)nullptr, cm, D, 0);
        lrelu_ln<<<gE4, blk, 0, stream>>>(c2p, gf, bf, c2n, cm);
        gemm2<1><<<g2a, blk2, 0, stream>>>(c2n, w3h, b3, c3, cm, 3 * D, D);
        gemm2<1><<<g2a, blk2, 0, stream>>>(c3, w4h, b4, c4, cm, 3 * D, 3 * D);
        gemm2<0><<<g2b, blk2, 0, stream>>>(c4, w5h, b5, c5, cm, D, 3 * D);
        final_k<<<gE4, blk, 0, stream>>>(c5, c2n, gfin, bfin, Wvec, bvec,
                                         (float*)d_out, e0, cm);
    }
}